// Round 3
// baseline (142.620 us; speedup 1.0000x reference)
//
#include <hip/hip_runtime.h>

// Morphological max-plus dilation, 'same' padding, K=5.
// out[b,o,y,x] = max_{c,i,j} f[b,c,y+i-2,x+j-2] + h[o,c,i,j]
// f(8,32,96,96) fp32, h(32,32,5,5) fp32, out(8,32,96,96) fp32.
//
// R18 = R17 + SGPR-operand elimination test. Evidence: VALU busy time is
// invariant at 48us across R15/R16/R17 (88.6x54.5% = 81.4x59.3% = 79.1x60.7%)
// and did NOT respond to +33% occupancy (R17) -> the pk pipe itself runs at
// ~4.15 cyc/instr, 2x the SIMD-32 VOP3P issue rate (m07: v_fma_f32 ~2cyc).
// Theory: the "s" source on v_pk_add_f16 (constant-bus read every other
// instr) blocks back-to-back VOP3P pipelining. Fix: per phase, broadcast the
// 10 h dwords SGPR->VGPR (10x v_mov_b32, +12% instrs), making all pk ops
// v,v,v. Also: in-place add/max (drops 8 t-temp VGPRs; 8 independent acc
// chains give the scheduler ILP), keeping the R17 dbuf pipeline (1-phase
// leads proven sufficient: occupancy response was flat).
// Predict: theory right -> dilate_main 52-60us, busy-time 48->~30us.
//          theory wrong -> ~80-84us flat => pk=4cyc is HW; next = dtype swap.

#define B_ 8
#define C_ 32
#define O_ 32
#define H_ 96
#define W_ 96
#define K_ 5
#define KK_ (K_ * K_)      // 25
#define NCP_ (C_ / 2)      // 16 c-pairs

#define TX_ 24             // threads along x; 24*4 = 96 = W
#define RT_ 8              // row-threads per group (8 output rows per block)
#define CS_ 2              // c-split groups (WAVE-ALIGNED: 192 thr = 3 waves)
#define TY_ (RT_ * CS_)    // 16
#define NT_ (TX_ * TY_)    // 384 threads = 6 waves
#define XR_ 4              // x outputs per thread
#define OB_ 2              // o-channels per block
#define NOG_ (O_ / OB_)    // 16 o-groups
#define CPG_ (NCP_ / CS_)  // 8 c-pairs per group

// padded f: [b][cp][PH][PW] dwords; row = y+2 (0..99), col = x+2 (pad to 104)
#define PH_ 100
#define PW_ 104
#define PLSZ_ (PH_ * PW_)
#define FPAD_BYTES ((size_t)B_ * NCP_ * PLSZ_ * 4)   // ~5.3 MB

// packed h in d_ws after fpad: [og][cp] blocks of 128 dwords.
// 5 phases per block, 16 dwords each (10 used):
// dword[p*16 + j*2 + o] = h2(h[og*2+o][2cp][5p+j], h[og*2+o][2cp+1][5p+j])
#define HBLK_ 128
#define HPH_ 16
#define HPACK_DW (NOG_ * NCP_ * HBLK_)               // 32768 dw = 128 KB

#define NEGF (-30000.0f)

typedef _Float16 h2 __attribute__((ext_vector_type(2)));
typedef int sv8 __attribute__((ext_vector_type(8)));
typedef int sv2 __attribute__((ext_vector_type(2)));
typedef unsigned uv4 __attribute__((ext_vector_type(4)));

static __device__ __forceinline__ h2 h2b(unsigned u) {
    return __builtin_bit_cast(h2, u);
}
static __device__ __forceinline__ unsigned bh2(h2 v) {
    return __builtin_bit_cast(unsigned, v);
}

// acc = pk_max(acc, fv + hv) -- ALL-VGPR operands (no constant-bus read).
static __device__ __forceinline__ void pk_addmax_v(h2& acc, h2 fv, int hv) {
    h2 t;
    asm("v_pk_add_f16 %0, %1, %2" : "=v"(t) : "v"(fv), "v"(hv));
    asm("v_pk_max_f16 %0, %1, %2" : "=v"(acc) : "v"(acc), "v"(t));
}

// dword d (0..7) of a window row held as two uv4 (static d after unroll).
static __device__ __forceinline__ h2 getwin(uv4 a, uv4 b, int d) {
    if (d == 0) return h2b(a[0]);
    if (d == 1) return h2b(a[1]);
    if (d == 2) return h2b(a[2]);
    if (d == 3) return h2b(a[3]);
    if (d == 4) return h2b(b[0]);
    if (d == 5) return h2b(b[1]);
    if (d == 6) return h2b(b[2]);
    return h2b(b[3]);
}

// one phase: row p of the window (j = 0..4), 2 o-channels, 4 x each.
// 8 independent acc chains per j -> scheduler has ILP without temps.
static __device__ __forceinline__ void compute_phase(h2 (&acc)[OB_][XR_],
        uv4 wa, uv4 wb, const int (&hv)[10]) {
#pragma unroll
    for (int j = 0; j < K_; ++j) {
        const int h0 = hv[j * 2];
        const int h1 = hv[j * 2 + 1];
#pragma unroll
        for (int xx = 0; xx < XR_; ++xx) {
            h2 fv = getwin(wa, wb, xx + j);
            pk_addmax_v(acc[0][xx], fv, h0);
            pk_addmax_v(acc[1][xx], fv, h1);
        }
    }
}

// issue one h phase (10 dwords: x8 + x2, 32B/8B-aligned offsets)
#define HLOADM(B0, B1, HP, O0S, O1S)                                   \
    asm volatile("s_load_dwordx8 %0, %2, " O0S "\n\t"                  \
                 "s_load_dwordx2 %1, %2, " O1S                         \
                 : "=s"(B0), "=s"(B1) : "s"(HP))

// issue one window row (2 vector loads, row offset folded into immediate)
#define WLOADM(SA, SB, PTR, O0S, O1S)                                  \
    asm volatile("global_load_dwordx4 %0, %2, off offset:" O0S "\n\t"  \
                 "global_load_dwordx4 %1, %2, off offset:" O1S         \
                 : "=v"(SA), "=v"(SB) : "v"(PTR))

// broadcast the 10 h dwords of the current phase SGPR -> VGPR.
#define BCAST(CH0, CH1)                                                   \
    do {                                                                  \
        asm("v_mov_b32 %0, %1" : "=v"(hv[0]) : "s"(CH0[0]));              \
        asm("v_mov_b32 %0, %1" : "=v"(hv[1]) : "s"(CH0[1]));              \
        asm("v_mov_b32 %0, %1" : "=v"(hv[2]) : "s"(CH0[2]));              \
        asm("v_mov_b32 %0, %1" : "=v"(hv[3]) : "s"(CH0[3]));              \
        asm("v_mov_b32 %0, %1" : "=v"(hv[4]) : "s"(CH0[4]));              \
        asm("v_mov_b32 %0, %1" : "=v"(hv[5]) : "s"(CH0[5]));              \
        asm("v_mov_b32 %0, %1" : "=v"(hv[6]) : "s"(CH0[6]));              \
        asm("v_mov_b32 %0, %1" : "=v"(hv[7]) : "s"(CH0[7]));              \
        asm("v_mov_b32 %0, %1" : "=v"(hv[8]) : "s"(CH1[0]));              \
        asm("v_mov_b32 %0, %1" : "=v"(hv[9]) : "s"(CH1[1]));              \
    } while (0)

// Steady-state phase:
//  1. lgkmcnt(0): current h buffer ready (issued one phase ago)
//  2. issue next phase's h loads into the other h buffer
//  3. issue next phase's window row into the other win buffer
//  4. vmcnt(2): current row (issued one phase ago) retired; next in flight
//  5. broadcast h SGPR->VGPR (10 movs)
//  6. compute (80 all-VGPR pk instrs)
// Volatile order pins the issues BEFORE the vmcnt wait -> guaranteed
// 1-phase lead. Register ties order consumers after the waits (rule #18).
#define PHASE(CH0, CH1, NH0, NH1, NHP, HO0, HO1, CW, NW, NPTR, WO0, WO1) \
    do {                                                                  \
        asm volatile("s_waitcnt lgkmcnt(0)" : "+s"(CH0), "+s"(CH1));      \
        HLOADM(NH0, NH1, NHP, HO0, HO1);                                  \
        WLOADM(NW[0], NW[1], NPTR, WO0, WO1);                             \
        asm volatile("s_waitcnt vmcnt(2)" : "+v"(CW[0]), "+v"(CW[1]));    \
        BCAST(CH0, CH1);                                                  \
        compute_phase(acc, CW[0], CW[1], hv);                             \
    } while (0)

// ---------------- merged pre-pass: pad/pack f + pack h -----------------------
__global__ __launch_bounds__(256)
void prep_kernel(const float* __restrict__ f, const float* __restrict__ h,
                 unsigned* __restrict__ fpad, unsigned* __restrict__ hpack) {
    const int bz = blockIdx.z;
    if (bz < B_) {
        const int idx = blockIdx.x * 256 + threadIdx.x;
        const int cp = blockIdx.y;            // 0..15
        if (idx >= PLSZ_) return;
        const int row = idx / PW_;
        const int col = idx - row * PW_;
        const int y = row - 2;
        const int x = col - 2;
        float v0 = NEGF, v1 = NEGF;
        if ((unsigned)y < H_ && (unsigned)x < W_) {
            v0 = f[((size_t)(bz * C_ + 2 * cp)     * H_ + y) * W_ + x];
            v1 = f[((size_t)(bz * C_ + 2 * cp + 1) * H_ + y) * W_ + x];
        }
        h2 d; d.x = (_Float16)v0; d.y = (_Float16)v1;
        fpad[(size_t)(bz * NCP_ + cp) * PLSZ_ + idx] = bh2(d);
    } else {
        const int t = (blockIdx.y * gridDim.x + blockIdx.x) * 256 + threadIdx.x;
        if (t >= NOG_ * NCP_ * KK_ * OB_) return;
        const int og = t / (NCP_ * KK_ * OB_);
        int r  = t - og * (NCP_ * KK_ * OB_);
        const int cp = r / (KK_ * OB_);
        r -= cp * (KK_ * OB_);
        const int ij = r / OB_;
        const int o  = r - ij * OB_;
        const int p  = ij / K_;
        const int jj = ij - p * K_;
        float a0 = h[((size_t)(og * OB_ + o) * C_ + 2 * cp)     * KK_ + ij];
        float a1 = h[((size_t)(og * OB_ + o) * C_ + 2 * cp + 1) * KK_ + ij];
        h2 pv; pv.x = (_Float16)a0; pv.y = (_Float16)a1;
        hpack[(size_t)(og * NCP_ + cp) * HBLK_ + p * HPH_ + jj * OB_ + o] = bh2(pv);
    }
}

// ---------------- main kernel ------------------------------------------------
__global__ __launch_bounds__(NT_, 7)
void dilate_main(const unsigned* __restrict__ fpad,
                 const unsigned* __restrict__ hpack,
                 float* __restrict__ out) {
    const int tx  = threadIdx.x;           // 0..23
    const int ty  = threadIdx.y;           // 0..15
    const int ry  = ty & (RT_ - 1);        // 0..7
    const int g   = ty >> 3;               // 0..1, wave-uniform (192-thr groups)
    const int gu  = __builtin_amdgcn_readfirstlane(g);

    const int ytile = blockIdx.x;          // 0..11
    const int og    = blockIdx.y;          // 0..15
    const int b     = blockIdx.z;          // 0..7
    const int y0 = ytile * RT_;
    const int o0 = og * OB_;
    const int x0 = XR_ * tx;               // 0..92
    const int yb = y0 + ry;

    __shared__ unsigned short comb[OB_ * XR_][RT_ * TX_];   // 8 x 192 x 2 = 3072 B

    h2 acc[OB_][XR_];
    {
        h2 neg; neg.x = (_Float16)NEGF; neg.y = (_Float16)NEGF;
#pragma unroll
        for (int o = 0; o < OB_; ++o)
#pragma unroll
            for (int xx = 0; xx < XR_; ++xx) acc[o][xx] = neg;
    }

    const int cp0v = g * CPG_;    // vector copy for window addressing
    const int cp0s = gu * CPG_;   // scalar copy for h addressing
    const unsigned* hpb = hpack + (size_t)(og * NCP_ + cp0s) * HBLK_;
    const unsigned* pvb = fpad + (size_t)(b * NCP_ + cp0v) * PLSZ_ + yb * PW_ + x0;

    sv8 hA0; sv2 hA1;           // "even" phase h buffer (10 dw)
    sv8 hB0; sv2 hB1;           // "odd" phase h buffer
    uv4 winA[2], winB[2];       // 2 row buffers, 8 dwords each
    int hv[10];                 // VGPR broadcast of current phase's h

    // prologue: h phase 0 of cp 0; window row 0 of cp 0 into winA.
    // vm outstanding entering loop = 2; each phase issues 2 then waits vmcnt(2).
    HLOADM(hA0, hA1, hpb, "0x0", "0x20");
    WLOADM(winA[0], winA[1], pvb, "0", "16");

#pragma unroll 1
    for (int cpi = 0; cpi < CPG_; cpi += 2) {
        const unsigned* hb0 = hpb + (size_t)cpi * HBLK_;
        const unsigned* hb1 = hb0 + HBLK_;
        const unsigned* hb2 = (cpi + 2 < CPG_) ? hb1 + HBLK_ : hb1;   // tail clamp
        const unsigned* pv0 = pvb + (size_t)cpi * PLSZ_;
        const unsigned* pv1 = pv0 + PLSZ_;
        const unsigned* pv2 = (cpi + 2 < CPG_) ? pv1 + PLSZ_ : pv1;   // tail clamp

        // k: body phase 0..9 (cp pair, 5 rows each); prefetch = phase k+1.
        // row offsets: r*PW_*4 = r*416 (+16 for second half).
        PHASE(hA0,hA1, hB0,hB1, hb0, "0x40","0x60",   winA, winB, pv0, "416","432");
        PHASE(hB0,hB1, hA0,hA1, hb0, "0x80","0xa0",   winB, winA, pv0, "832","848");
        PHASE(hA0,hA1, hB0,hB1, hb0, "0xc0","0xe0",   winA, winB, pv0, "1248","1264");
        PHASE(hB0,hB1, hA0,hA1, hb0, "0x100","0x120", winB, winA, pv0, "1664","1680");
        PHASE(hA0,hA1, hB0,hB1, hb1, "0x0","0x20",    winA, winB, pv1, "0","16");
        PHASE(hB0,hB1, hA0,hA1, hb1, "0x40","0x60",   winB, winA, pv1, "416","432");
        PHASE(hA0,hA1, hB0,hB1, hb1, "0x80","0xa0",   winA, winB, pv1, "832","848");
        PHASE(hB0,hB1, hA0,hA1, hb1, "0xc0","0xe0",   winB, winA, pv1, "1248","1264");
        PHASE(hA0,hA1, hB0,hB1, hb1, "0x100","0x120", winA, winB, pv1, "1664","1680");
        PHASE(hB0,hB1, hA0,hA1, hb2, "0x0","0x20",    winB, winA, pv2, "0","16");
    }

    // Drain the tail's in-flight junk prefetches (winA row + hA phase)
    // BEFORE regalloc may reuse those registers in the epilogue.
    asm volatile("s_waitcnt vmcnt(0) lgkmcnt(0)"
                 : "+v"(winA[0]), "+v"(winA[1]), "+s"(hA0), "+s"(hA1));

    // ---- reduce c-pair halves to scalar fp16 ---------------------------------
    unsigned short red[OB_][XR_];
#pragma unroll
    for (int o = 0; o < OB_; ++o)
#pragma unroll
        for (int xx = 0; xx < XR_; ++xx) {
            _Float16 a = acc[o][xx].x;
            _Float16 b2 = acc[o][xx].y;
            _Float16 m = (a > b2) ? a : b2;
            red[o][xx] = __builtin_bit_cast(unsigned short, m);
        }

    // ---- combine the two c-groups via LDS ------------------------------------
    const int t192 = ry * TX_ + tx;   // 0..191 within group
    if (g == 1) {
#pragma unroll
        for (int o = 0; o < OB_; ++o)
#pragma unroll
            for (int xx = 0; xx < XR_; ++xx)
                comb[o * XR_ + xx][t192] = red[o][xx];
    }
    __syncthreads();
    if (g == 0) {
        const int y = yb;
#pragma unroll
        for (int o = 0; o < OB_; ++o) {
            float r[XR_];
#pragma unroll
            for (int xx = 0; xx < XR_; ++xx) {
                _Float16 m  = __builtin_bit_cast(_Float16, red[o][xx]);
                _Float16 v0 = __builtin_bit_cast(_Float16,
                                                 comb[o * XR_ + xx][t192]);
                m = (v0 > m) ? v0 : m;
                r[xx] = (float)m;
            }
            float4 v = make_float4(r[0], r[1], r[2], r[3]);
            *(float4*)&out[(((size_t)b * O_ + (o0 + o)) * H_ + y) * W_ + x0] = v;
        }
    }
}

// ---------------- fallback (no workspace): correctness-only ------------------
__global__ __launch_bounds__(256)
void dilate_naive(const float* __restrict__ f, const float* __restrict__ h,
                  float* __restrict__ out) {
    const int idx = blockIdx.x * 256 + threadIdx.x;
    if (idx >= B_ * O_ * H_ * W_) return;
    const int x = idx % W_;
    const int y = (idx / W_) % H_;
    const int o = (idx / (W_ * H_)) % O_;
    const int b = idx / (W_ * H_ * O_);
    float m = -3.0e38f;
    for (int c = 0; c < C_; ++c)
        for (int i = 0; i < K_; ++i)
            for (int j = 0; j < K_; ++j) {
                int yy = y + i - 2, xc = x + j - 2;
                if ((unsigned)yy < H_ && (unsigned)xc < W_) {
                    float v = f[((size_t)(b * C_ + c) * H_ + yy) * W_ + xc] +
                              h[((size_t)o * C_ + c) * KK_ + i * K_ + j];
                    m = fmaxf(m, v);
                }
            }
    out[idx] = m;
}

extern "C" void kernel_launch(void* const* d_in, const int* in_sizes, int n_in,
                              void* d_out, int out_size, void* d_ws, size_t ws_size,
                              hipStream_t stream) {
    const float* f = (const float*)d_in[0];
    const float* h = (const float*)d_in[1];
    float* out = (float*)d_out;

    const size_t need = FPAD_BYTES + (size_t)HPACK_DW * 4;
    if (ws_size >= need) {
        unsigned* fpad  = (unsigned*)d_ws;
        unsigned* hpack = (unsigned*)((char*)d_ws + FPAD_BYTES);
        dim3 pgrid((PLSZ_ + 255) / 256, NCP_, B_ + 1);   // z=B_ slice packs h
        hipLaunchKernelGGL(prep_kernel, pgrid, dim3(256), 0, stream,
                           f, h, fpad, hpack);
        dim3 mgrid(H_ / RT_, NOG_, B_);       // (12, 16, 8) = 1536 blocks
        dim3 mblock(TX_, TY_);                // 384 threads = 6 waves
        hipLaunchKernelGGL(dilate_main, mgrid, mblock, 0, stream,
                           fpad, hpack, out);
    } else {
        hipLaunchKernelGGL(dilate_naive,
                           dim3((B_ * O_ * H_ * W_ + 255) / 256), dim3(256),
                           0, stream, f, h, out);
    }
}

// Round 4
// 137.051 us; speedup vs baseline: 1.0406x; 1.0406x over previous
//
#include <hip/hip_runtime.h>

// Morphological max-plus dilation, 'same' padding, K=5.
// out[b,o,y,x] = max_{c,i,j} f[b,c,y+i-2,x+j-2] + h[o,c,i,j]
// f(8,32,96,96) fp32, h(32,32,5,5) fp32, out(8,32,96,96) fp32.
//
// R19. Evidence ledger:
//  - pk issue rate invariant ~1.67ns/wave-instr (R15-R18: busy = instrs x
//    1.67ns regardless of SGPR/VGPR operands, occupancy, pipeline shape).
//    R18's +10 movs/phase raised busy by exactly their count -> operand
//    type irrelevant. Busy floor ~48us; idle ~31us is the only target.
//  - FETCH 8.2MB ~= full fpad re-read: og-reuse served by L3 (>4MB/XCD),
//    latency ~500-900cyc > the 1-phase (~300cyc-at-best) prefetch lead.
//    R16 had 4-phase lead but 3 waves/SIMD; R17 had waves but 1-phase lead.
// R19 = deep lead AND occupancy: superphase (2 rows) double-buffering.
//  - win: 2 bufs x 2 rows (32 VGPR), counted s_waitcnt vmcnt(4), lead =
//    one superphase ~= 2 phase-walls (~1400cyc) >= L3 latency.
//  - h: 2 SGPR bufs x 2 slots (40 SGPR), one lgkmcnt(0) per superphase
//    draining loads issued a full superphase earlier (OOO-safe: single
//    drain point).
//  - body = 4 cps = 10 superphases (even -> static buffer parity);
//    iteration N's last prefetch IS iteration N+1's first data; only the
//    final superphase of the last iteration prefetches clamped junk.
//  - VGPR ~60 (h in SGPRs, no hv broadcast) -> launch_bounds(384,7),
//    target 7 waves/SIMD, 4-5 blocks/CU.
// Predict: dilate_main 56-64us, VALUBusy 75-85%, Occupancy 60-80%,
// FETCH/WRITE unchanged. If idle persists at full lead+occupancy, the
// remaining gap is structural -> floor reached.

#define B_ 8
#define C_ 32
#define O_ 32
#define H_ 96
#define W_ 96
#define K_ 5
#define KK_ (K_ * K_)      // 25
#define NCP_ (C_ / 2)      // 16 c-pairs

#define TX_ 24             // threads along x; 24*4 = 96 = W
#define RT_ 8              // row-threads per group (8 output rows per block)
#define CS_ 2              // c-split groups (WAVE-ALIGNED: 192 thr = 3 waves)
#define TY_ (RT_ * CS_)    // 16
#define NT_ (TX_ * TY_)    // 384 threads = 6 waves
#define XR_ 4              // x outputs per thread
#define OB_ 2              // o-channels per block
#define NOG_ (O_ / OB_)    // 16 o-groups
#define CPG_ (NCP_ / CS_)  // 8 c-pairs per group

// padded f: [b][cp][PH][PW] dwords; row = y+2 (0..99), col = x+2 (pad to 104)
#define PH_ 100
#define PW_ 104
#define PLSZ_ (PH_ * PW_)
#define FPAD_BYTES ((size_t)B_ * NCP_ * PLSZ_ * 4)   // ~5.3 MB

// packed h in d_ws after fpad: [og][cp] blocks of 128 dwords.
// 5 slots (rows) per block, 16 dwords each (10 used):
// dword[p*16 + j*2 + o] = h2(h[og*2+o][2cp][5p+j], h[og*2+o][2cp+1][5p+j])
#define HBLK_ 128
#define HPH_ 16
#define HPACK_DW (NOG_ * NCP_ * HBLK_)               // 32768 dw = 128 KB

#define NEGF (-30000.0f)

typedef _Float16 h2 __attribute__((ext_vector_type(2)));
typedef int sv8 __attribute__((ext_vector_type(8)));
typedef int sv2 __attribute__((ext_vector_type(2)));
typedef unsigned uv4 __attribute__((ext_vector_type(4)));

static __device__ __forceinline__ h2 h2b(unsigned u) {
    return __builtin_bit_cast(h2, u);
}
static __device__ __forceinline__ unsigned bh2(h2 v) {
    return __builtin_bit_cast(unsigned, v);
}

// acc = pk_max(acc, fv + h) with h from an SGPR (proven rate-neutral, R18).
static __device__ __forceinline__ void pk_addmax_s(h2& acc, h2 fv, int hs) {
    h2 t;
    asm("v_pk_add_f16 %0, %1, %2" : "=v"(t) : "v"(fv), "s"(hs));
    asm("v_pk_max_f16 %0, %1, %2" : "=v"(acc) : "v"(acc), "v"(t));
}

// dword d (0..7) of a window row held as two uv4 (static d after unroll).
static __device__ __forceinline__ h2 getwin(uv4 a, uv4 b, int d) {
    if (d == 0) return h2b(a[0]);
    if (d == 1) return h2b(a[1]);
    if (d == 2) return h2b(a[2]);
    if (d == 3) return h2b(a[3]);
    if (d == 4) return h2b(b[0]);
    if (d == 5) return h2b(b[1]);
    if (d == 6) return h2b(b[2]);
    return h2b(b[3]);
}

// one row-phase: j = 0..4, 2 o-channels, 4 x each -> 40 addmax = 80 pk.
static __device__ __forceinline__ void compute_row(h2 (&acc)[OB_][XR_],
        uv4 wa, uv4 wb, sv8 c0, sv2 c1) {
#pragma unroll
    for (int j = 0; j < K_; ++j) {
        const int h0 = (j * 2 < 8) ? c0[j * 2] : c1[j * 2 - 8];
        const int h1 = (j * 2 + 1 < 8) ? c0[j * 2 + 1] : c1[j * 2 + 1 - 8];
#pragma unroll
        for (int xx = 0; xx < XR_; ++xx) {
            h2 fv = getwin(wa, wb, xx + j);
            pk_addmax_s(acc[0][xx], fv, h0);
            pk_addmax_s(acc[1][xx], fv, h1);
        }
    }
}

// issue one superphase of h: two 16-dw slots, 10 dw used each (x8 + x2).
#define HLOAD2(B0, B1, B2, B3, HQ, O0S, O1S, O2S, O3S)                 \
    asm volatile("s_load_dwordx8 %0, %4, " O0S "\n\t"                  \
                 "s_load_dwordx2 %1, %4, " O1S "\n\t"                  \
                 "s_load_dwordx8 %2, %4, " O2S "\n\t"                  \
                 "s_load_dwordx2 %3, %4, " O3S                         \
                 : "=s"(B0), "=s"(B1), "=s"(B2), "=s"(B3) : "s"(HQ))

// issue one superphase of windows: two rows x two dwordx4.
#define WLOAD2(WB, PA, OA0, OA1, PB, OB0, OB1)                         \
    asm volatile("global_load_dwordx4 %0, %4, off offset:" OA0 "\n\t"  \
                 "global_load_dwordx4 %1, %4, off offset:" OA1 "\n\t"  \
                 "global_load_dwordx4 %2, %5, off offset:" OB0 "\n\t"  \
                 "global_load_dwordx4 %3, %5, off offset:" OB1         \
                 : "=v"(WB[0]), "=v"(WB[1]), "=v"(WB[2]), "=v"(WB[3])  \
                 : "v"(PA), "v"(PB))

// Steady-state superphase:
//  1. lgkmcnt(0): current h slots ready (issued one superphase ago)
//  2. issue next superphase's h into the other SGPR buffer
//  3. issue next superphase's 2 window rows into the other win buffer
//  4. vmcnt(4): current rows (issued one superphase ago) retired
//  5. compute 2 row-phases (160 pk instrs)
// Lead for every wait = one full superphase (~1400+ cyc) >= L3 latency.
#define SUPER(CH0, CH1, CH2, CH3, NH0, NH1, NH2, NH3, HQ, O0S, O1S, O2S, O3S, \
              CW, NW, PA, OA0, OA1, PB, OB0, OB1)                             \
    do {                                                                      \
        asm volatile("s_waitcnt lgkmcnt(0)"                                   \
                     : "+s"(CH0), "+s"(CH1), "+s"(CH2), "+s"(CH3));           \
        HLOAD2(NH0, NH1, NH2, NH3, HQ, O0S, O1S, O2S, O3S);                   \
        WLOAD2(NW, PA, OA0, OA1, PB, OB0, OB1);                               \
        asm volatile("s_waitcnt vmcnt(4)"                                     \
                     : "+v"(CW[0]), "+v"(CW[1]), "+v"(CW[2]), "+v"(CW[3]));   \
        compute_row(acc, CW[0], CW[1], CH0, CH1);                             \
        compute_row(acc, CW[2], CW[3], CH2, CH3);                             \
    } while (0)

// ---------------- merged pre-pass: pad/pack f + pack h -----------------------
__global__ __launch_bounds__(256)
void prep_kernel(const float* __restrict__ f, const float* __restrict__ h,
                 unsigned* __restrict__ fpad, unsigned* __restrict__ hpack) {
    const int bz = blockIdx.z;
    if (bz < B_) {
        const int idx = blockIdx.x * 256 + threadIdx.x;
        const int cp = blockIdx.y;            // 0..15
        if (idx >= PLSZ_) return;
        const int row = idx / PW_;
        const int col = idx - row * PW_;
        const int y = row - 2;
        const int x = col - 2;
        float v0 = NEGF, v1 = NEGF;
        if ((unsigned)y < H_ && (unsigned)x < W_) {
            v0 = f[((size_t)(bz * C_ + 2 * cp)     * H_ + y) * W_ + x];
            v1 = f[((size_t)(bz * C_ + 2 * cp + 1) * H_ + y) * W_ + x];
        }
        h2 d; d.x = (_Float16)v0; d.y = (_Float16)v1;
        fpad[(size_t)(bz * NCP_ + cp) * PLSZ_ + idx] = bh2(d);
    } else {
        const int t = (blockIdx.y * gridDim.x + blockIdx.x) * 256 + threadIdx.x;
        if (t >= NOG_ * NCP_ * KK_ * OB_) return;
        const int og = t / (NCP_ * KK_ * OB_);
        int r  = t - og * (NCP_ * KK_ * OB_);
        const int cp = r / (KK_ * OB_);
        r -= cp * (KK_ * OB_);
        const int ij = r / OB_;
        const int o  = r - ij * OB_;
        const int p  = ij / K_;
        const int jj = ij - p * K_;
        float a0 = h[((size_t)(og * OB_ + o) * C_ + 2 * cp)     * KK_ + ij];
        float a1 = h[((size_t)(og * OB_ + o) * C_ + 2 * cp + 1) * KK_ + ij];
        h2 pv; pv.x = (_Float16)a0; pv.y = (_Float16)a1;
        hpack[(size_t)(og * NCP_ + cp) * HBLK_ + p * HPH_ + jj * OB_ + o] = bh2(pv);
    }
}

// ---------------- main kernel ------------------------------------------------
__global__ __launch_bounds__(NT_, 7)
void dilate_main(const unsigned* __restrict__ fpad,
                 const unsigned* __restrict__ hpack,
                 float* __restrict__ out) {
    const int tx  = threadIdx.x;           // 0..23
    const int ty  = threadIdx.y;           // 0..15
    const int ry  = ty & (RT_ - 1);        // 0..7
    const int g   = ty >> 3;               // 0..1, wave-uniform (192-thr groups)
    const int gu  = __builtin_amdgcn_readfirstlane(g);

    const int ytile = blockIdx.x;          // 0..11
    const int og    = blockIdx.y;          // 0..15
    const int b     = blockIdx.z;          // 0..7
    const int y0 = ytile * RT_;
    const int o0 = og * OB_;
    const int x0 = XR_ * tx;               // 0..92
    const int yb = y0 + ry;

    __shared__ unsigned short comb[OB_ * XR_][RT_ * TX_];   // 8 x 192 x 2 = 3072 B

    h2 acc[OB_][XR_];
    {
        h2 neg; neg.x = (_Float16)NEGF; neg.y = (_Float16)NEGF;
#pragma unroll
        for (int o = 0; o < OB_; ++o)
#pragma unroll
            for (int xx = 0; xx < XR_; ++xx) acc[o][xx] = neg;
    }

    const int cp0v = g * CPG_;    // vector copy for window addressing
    const int cp0s = gu * CPG_;   // scalar copy for h addressing
    const unsigned* hpb = hpack + (size_t)(og * NCP_ + cp0s) * HBLK_;
    const unsigned* pvb = fpad + (size_t)(b * NCP_ + cp0v) * PLSZ_ + yb * PW_ + x0;

    sv8 hA0, hA2, hB0, hB2;     // h superphase buffers: 2 slots each
    sv2 hA1, hA3, hB1, hB3;
    uv4 winA[4], winB[4];       // win superphase buffers: 2 rows x 2 dwordx4

    // prologue: superphase 0 (cp0 rows 0,1) into the A buffers.
    // vm outstanding entering loop = 4; invariant: each superphase issues 4
    // then waits vmcnt(4).
    HLOAD2(hA0, hA1, hA2, hA3, hpb, "0x0", "0x20", "0x40", "0x60");
    WLOAD2(winA, pvb, "0", "16", pvb, "416", "432");

    // body: 4 cps = 10 superphases per iteration (even -> static parity).
    // h slot (c,r) byte offset = c*512 + r*64 (+0x20 for the x2 part).
    // win row r byte offset = r*416 (+16 for the second dwordx4).
#pragma unroll 1
    for (int cpi = 0; cpi < CPG_; cpi += 4) {
        const unsigned* pv0 = pvb + (size_t)cpi * PLSZ_;
        const unsigned* pv1 = pv0 + PLSZ_;
        const unsigned* pv2 = pv1 + PLSZ_;
        const unsigned* pv3 = pv2 + PLSZ_;
        const bool last = (cpi + 4 >= CPG_);
        const unsigned* pv4 = last ? pv0 : pv3 + PLSZ_;          // tail clamp
        const unsigned* hq  = hpb + (size_t)cpi * HBLK_;
        const unsigned* hq2 = last ? hq : hq + 4 * (size_t)HBLK_; // tail clamp

        // sp0: compute c0{r0,r1}; prefetch c0{r2,r3}
        SUPER(hA0,hA1,hA2,hA3, hB0,hB1,hB2,hB3, hq, "0x80","0xa0","0xc0","0xe0",
              winA, winB, pv0, "832","848",  pv0, "1248","1264");
        // sp1: compute c0{r2,r3}; prefetch c0r4, c1r0
        SUPER(hB0,hB1,hB2,hB3, hA0,hA1,hA2,hA3, hq, "0x100","0x120","0x200","0x220",
              winB, winA, pv0, "1664","1680", pv1, "0","16");
        // sp2: compute c0r4, c1r0; prefetch c1{r1,r2}
        SUPER(hA0,hA1,hA2,hA3, hB0,hB1,hB2,hB3, hq, "0x240","0x260","0x280","0x2a0",
              winA, winB, pv1, "416","432",  pv1, "832","848");
        // sp3: compute c1{r1,r2}; prefetch c1{r3,r4}
        SUPER(hB0,hB1,hB2,hB3, hA0,hA1,hA2,hA3, hq, "0x2c0","0x2e0","0x300","0x320",
              winB, winA, pv1, "1248","1264", pv1, "1664","1680");
        // sp4: compute c1{r3,r4}; prefetch c2{r0,r1}
        SUPER(hA0,hA1,hA2,hA3, hB0,hB1,hB2,hB3, hq, "0x400","0x420","0x440","0x460",
              winA, winB, pv2, "0","16",     pv2, "416","432");
        // sp5: compute c2{r0,r1}; prefetch c2{r2,r3}
        SUPER(hB0,hB1,hB2,hB3, hA0,hA1,hA2,hA3, hq, "0x480","0x4a0","0x4c0","0x4e0",
              winB, winA, pv2, "832","848",  pv2, "1248","1264");
        // sp6: compute c2{r2,r3}; prefetch c2r4, c3r0
        SUPER(hA0,hA1,hA2,hA3, hB0,hB1,hB2,hB3, hq, "0x500","0x520","0x600","0x620",
              winA, winB, pv2, "1664","1680", pv3, "0","16");
        // sp7: compute c2r4, c3r0; prefetch c3{r1,r2}
        SUPER(hB0,hB1,hB2,hB3, hA0,hA1,hA2,hA3, hq, "0x640","0x660","0x680","0x6a0",
              winB, winA, pv3, "416","432",  pv3, "832","848");
        // sp8: compute c3{r1,r2}; prefetch c3{r3,r4}
        SUPER(hA0,hA1,hA2,hA3, hB0,hB1,hB2,hB3, hq, "0x6c0","0x6e0","0x700","0x720",
              winA, winB, pv3, "1248","1264", pv3, "1664","1680");
        // sp9: compute c3{r3,r4}; prefetch next iteration's c0{r0,r1}
        //      (real handoff data except on the last iteration = junk)
        SUPER(hB0,hB1,hB2,hB3, hA0,hA1,hA2,hA3, hq2, "0x0","0x20","0x40","0x60",
              winB, winA, pv4, "0","16",     pv4, "416","432");
    }

    // Drain the final junk prefetch (winA rows + hA slots) BEFORE regalloc
    // may reuse those registers in the epilogue.
    asm volatile("s_waitcnt vmcnt(0) lgkmcnt(0)"
                 : "+v"(winA[0]), "+v"(winA[1]), "+v"(winA[2]), "+v"(winA[3]),
                   "+s"(hA0), "+s"(hA1), "+s"(hA2), "+s"(hA3));

    // ---- reduce c-pair halves to scalar fp16 ---------------------------------
    unsigned short red[OB_][XR_];
#pragma unroll
    for (int o = 0; o < OB_; ++o)
#pragma unroll
        for (int xx = 0; xx < XR_; ++xx) {
            _Float16 a = acc[o][xx].x;
            _Float16 b2 = acc[o][xx].y;
            _Float16 m = (a > b2) ? a : b2;
            red[o][xx] = __builtin_bit_cast(unsigned short, m);
        }

    // ---- combine the two c-groups via LDS ------------------------------------
    const int t192 = ry * TX_ + tx;   // 0..191 within group
    if (g == 1) {
#pragma unroll
        for (int o = 0; o < OB_; ++o)
#pragma unroll
            for (int xx = 0; xx < XR_; ++xx)
                comb[o * XR_ + xx][t192] = red[o][xx];
    }
    __syncthreads();
    if (g == 0) {
        const int y = yb;
#pragma unroll
        for (int o = 0; o < OB_; ++o) {
            float r[XR_];
#pragma unroll
            for (int xx = 0; xx < XR_; ++xx) {
                _Float16 m  = __builtin_bit_cast(_Float16, red[o][xx]);
                _Float16 v0 = __builtin_bit_cast(_Float16,
                                                 comb[o * XR_ + xx][t192]);
                m = (v0 > m) ? v0 : m;
                r[xx] = (float)m;
            }
            float4 v = make_float4(r[0], r[1], r[2], r[3]);
            *(float4*)&out[(((size_t)b * O_ + (o0 + o)) * H_ + y) * W_ + x0] = v;
        }
    }
}

// ---------------- fallback (no workspace): correctness-only ------------------
__global__ __launch_bounds__(256)
void dilate_naive(const float* __restrict__ f, const float* __restrict__ h,
                  float* __restrict__ out) {
    const int idx = blockIdx.x * 256 + threadIdx.x;
    if (idx >= B_ * O_ * H_ * W_) return;
    const int x = idx % W_;
    const int y = (idx / W_) % H_;
    const int o = (idx / (W_ * H_)) % O_;
    const int b = idx / (W_ * H_ * O_);
    float m = -3.0e38f;
    for (int c = 0; c < C_; ++c)
        for (int i = 0; i < K_; ++i)
            for (int j = 0; j < K_; ++j) {
                int yy = y + i - 2, xc = x + j - 2;
                if ((unsigned)yy < H_ && (unsigned)xc < W_) {
                    float v = f[((size_t)(b * C_ + c) * H_ + yy) * W_ + xc] +
                              h[((size_t)o * C_ + c) * KK_ + i * K_ + j];
                    m = fmaxf(m, v);
                }
            }
    out[idx] = m;
}

extern "C" void kernel_launch(void* const* d_in, const int* in_sizes, int n_in,
                              void* d_out, int out_size, void* d_ws, size_t ws_size,
                              hipStream_t stream) {
    const float* f = (const float*)d_in[0];
    const float* h = (const float*)d_in[1];
    float* out = (float*)d_out;

    const size_t need = FPAD_BYTES + (size_t)HPACK_DW * 4;
    if (ws_size >= need) {
        unsigned* fpad  = (unsigned*)d_ws;
        unsigned* hpack = (unsigned*)((char*)d_ws + FPAD_BYTES);
        dim3 pgrid((PLSZ_ + 255) / 256, NCP_, B_ + 1);   // z=B_ slice packs h
        hipLaunchKernelGGL(prep_kernel, pgrid, dim3(256), 0, stream,
                           f, h, fpad, hpack);
        dim3 mgrid(H_ / RT_, NOG_, B_);       // (12, 16, 8) = 1536 blocks
        dim3 mblock(TX_, TY_);                // 384 threads = 6 waves
        hipLaunchKernelGGL(dilate_main, mgrid, mblock, 0, stream,
                           fpad, hpack, out);
    } else {
        hipLaunchKernelGGL(dilate_naive,
                           dim3((B_ * O_ * H_ * W_ + 255) / 256), dim3(256),
                           0, stream, f, h, out);
    }
}

// Round 5
// 134.686 us; speedup vs baseline: 1.0589x; 1.0176x over previous
//
#include <hip/hip_runtime.h>

// Morphological max-plus dilation, 'same' padding, K=5.
// out[b,o,y,x] = max_{c,i,j} f[b,c,y+i-2,x+j-2] + h[o,c,i,j]
// f(8,32,96,96) fp32, h(32,32,5,5) fp32, out(8,32,96,96) fp32.
//
// R20 = R17 structure (best measured: 79.1us) with the math pipe switched
// from packed-f16 to packed-i16 fixed point. Evidence ledger (R15-R19):
//  - busy-time = pk-instrs x 1.67ns, invariant to operands/occupancy/depth.
//  - total = busy x ~1.65-1.8, ALSO invariant: R18 (+12.5% instrs) raised
//    TOTAL ~11%, not just busy -> idle is NOT coverable latency; it is a
//    multiplicative ~2.6cyc shadow per pk instr. Deeper prefetch (R19
//    superphase lead) changed nothing; per-wave duty ~0.24 constant.
//  - hypothesis: the shadow is f16-VOP3P-pipe-specific. m07 measured plain
//    f32 VALU at 2cyc/wave-instr (half our pk rate). Test: v_pk_add_i16 /
//    v_pk_max_i16 (max-plus is order-isomorphic under monotone fixed-point
//    map). Scale 2048: f in +-11k, h in +-125, halo -30000; no wrap;
//    quant err ~2.4e-4 << 0.03 tolerance. fpad/hpack byte layout unchanged.
// Predict: i16 full-rate -> dur 45-60us (busy 24-28). Flat ~78-85 ->
// instruction floor is generic -> R17/R20 ~79us is the roofline.

#define B_ 8
#define C_ 32
#define O_ 32
#define H_ 96
#define W_ 96
#define K_ 5
#define KK_ (K_ * K_)      // 25
#define NCP_ (C_ / 2)      // 16 c-pairs

#define TX_ 24             // threads along x; 24*4 = 96 = W
#define RT_ 8              // row-threads per group (8 output rows per block)
#define CS_ 2              // c-split groups (WAVE-ALIGNED: 192 thr = 3 waves)
#define TY_ (RT_ * CS_)    // 16
#define NT_ (TX_ * TY_)    // 384 threads = 6 waves
#define XR_ 4              // x outputs per thread
#define OB_ 2              // o-channels per block
#define NOG_ (O_ / OB_)    // 16 o-groups
#define CPG_ (NCP_ / CS_)  // 8 c-pairs per group

// padded f: [b][cp][PH][PW] dwords; row = y+2 (0..99), col = x+2 (pad to 104)
#define PH_ 100
#define PW_ 104
#define PLSZ_ (PH_ * PW_)
#define FPAD_BYTES ((size_t)B_ * NCP_ * PLSZ_ * 4)   // ~5.3 MB

// packed h in d_ws after fpad: [og][cp] blocks of 128 dwords.
// 5 phases per block, 16 dwords each (10 used):
// dword[p*16 + j*2 + o] = pack_i16(hq[og*2+o][2cp][5p+j], hq[og*2+o][2cp+1][5p+j])
#define HBLK_ 128
#define HPH_ 16
#define HPACK_DW (NOG_ * NCP_ * HBLK_)               // 32768 dw = 128 KB

// fixed-point: value * 2048, round-to-nearest. halo = -30000 (beats nothing).
#define SCALE_ 2048.0f
#define INVSCALE_ (1.0f / 2048.0f)
#define NEGQ_ (-30000)
#define NEGPACK_ 0x8AD08AD0u   // (-30000 & 0xffff) | (-30000 << 16)

typedef int sv8 __attribute__((ext_vector_type(8)));
typedef int sv2 __attribute__((ext_vector_type(2)));
typedef unsigned uv4 __attribute__((ext_vector_type(4)));

static __device__ __forceinline__ int q16(float v) {
    int q = __float2int_rn(v * SCALE_);
    q = (q < -32768) ? -32768 : q;
    q = (q > 32767) ? 32767 : q;
    return q;
}
static __device__ __forceinline__ unsigned packq(int lo, int hi) {
    return (unsigned)(lo & 0xffff) | ((unsigned)hi << 16);
}

// acc = pk_max_i16(acc, fv +i16 h) with h from an SGPR.
static __device__ __forceinline__ void pk_addmax_s(int& acc, int fv, int hs) {
    int t;
    asm("v_pk_add_i16 %0, %1, %2" : "=v"(t) : "v"(fv), "s"(hs));
    asm("v_pk_max_i16 %0, %1, %2" : "=v"(acc) : "v"(acc), "v"(t));
}

// dword d (0..7) of a window row held as two uv4 (static d after unroll).
static __device__ __forceinline__ int getwin(uv4 a, uv4 b, int d) {
    if (d == 0) return (int)a[0];
    if (d == 1) return (int)a[1];
    if (d == 2) return (int)a[2];
    if (d == 3) return (int)a[3];
    if (d == 4) return (int)b[0];
    if (d == 5) return (int)b[1];
    if (d == 6) return (int)b[2];
    return (int)b[3];
}

// one phase: row p of the window (j = 0..4), 2 o-channels, 4 x each.
// 8 independent acc chains per j.
static __device__ __forceinline__ void compute_phase(int (&acc)[OB_][XR_],
        uv4 wa, uv4 wb, sv8 c0, sv2 c1) {
#pragma unroll
    for (int j = 0; j < K_; ++j) {
        const int h0 = (j * 2 < 8) ? c0[j * 2] : c1[j * 2 - 8];
        const int h1 = (j * 2 + 1 < 8) ? c0[j * 2 + 1] : c1[j * 2 + 1 - 8];
#pragma unroll
        for (int xx = 0; xx < XR_; ++xx) {
            int fv = getwin(wa, wb, xx + j);
            pk_addmax_s(acc[0][xx], fv, h0);
            pk_addmax_s(acc[1][xx], fv, h1);
        }
    }
}

// issue one h phase (10 dwords: x8 + x2, 32B/8B-aligned offsets)
#define HLOADM(B0, B1, HP, O0S, O1S)                                   \
    asm volatile("s_load_dwordx8 %0, %2, " O0S "\n\t"                  \
                 "s_load_dwordx2 %1, %2, " O1S                         \
                 : "=s"(B0), "=s"(B1) : "s"(HP))

// issue one window row (2 vector loads, row offset folded into immediate)
#define WLOADM(SA, SB, PTR, O0S, O1S)                                  \
    asm volatile("global_load_dwordx4 %0, %2, off offset:" O0S "\n\t"  \
                 "global_load_dwordx4 %1, %2, off offset:" O1S         \
                 : "=v"(SA), "=v"(SB) : "v"(PTR))

// Steady-state phase (R17-proven):
//  1. lgkmcnt(0): current h buffer ready (issued one phase ago)
//  2. issue next phase's h loads into the other h buffer
//  3. issue next phase's window row into the other win buffer
//  4. vmcnt(2): current row (issued one phase ago) retired; next in flight
//  5. compute (80 pk instrs)
#define PHASE(CH0, CH1, NH0, NH1, NHP, HO0, HO1, CW, NW, NPTR, WO0, WO1) \
    do {                                                                  \
        asm volatile("s_waitcnt lgkmcnt(0)" : "+s"(CH0), "+s"(CH1));      \
        HLOADM(NH0, NH1, NHP, HO0, HO1);                                  \
        WLOADM(NW[0], NW[1], NPTR, WO0, WO1);                             \
        asm volatile("s_waitcnt vmcnt(2)" : "+v"(CW[0]), "+v"(CW[1]));    \
        compute_phase(acc, CW[0], CW[1], CH0, CH1);                       \
    } while (0)

// ---------------- merged pre-pass: pad/pack f + pack h -----------------------
__global__ __launch_bounds__(256)
void prep_kernel(const float* __restrict__ f, const float* __restrict__ h,
                 unsigned* __restrict__ fpad, unsigned* __restrict__ hpack) {
    const int bz = blockIdx.z;
    if (bz < B_) {
        const int idx = blockIdx.x * 256 + threadIdx.x;
        const int cp = blockIdx.y;            // 0..15
        if (idx >= PLSZ_) return;
        const int row = idx / PW_;
        const int col = idx - row * PW_;
        const int y = row - 2;
        const int x = col - 2;
        unsigned pk = NEGPACK_;
        if ((unsigned)y < H_ && (unsigned)x < W_) {
            float v0 = f[((size_t)(bz * C_ + 2 * cp)     * H_ + y) * W_ + x];
            float v1 = f[((size_t)(bz * C_ + 2 * cp + 1) * H_ + y) * W_ + x];
            pk = packq(q16(v0), q16(v1));
        }
        fpad[(size_t)(bz * NCP_ + cp) * PLSZ_ + idx] = pk;
    } else {
        const int t = (blockIdx.y * gridDim.x + blockIdx.x) * 256 + threadIdx.x;
        if (t >= NOG_ * NCP_ * KK_ * OB_) return;
        const int og = t / (NCP_ * KK_ * OB_);
        int r  = t - og * (NCP_ * KK_ * OB_);
        const int cp = r / (KK_ * OB_);
        r -= cp * (KK_ * OB_);
        const int ij = r / OB_;
        const int o  = r - ij * OB_;
        const int p  = ij / K_;
        const int jj = ij - p * K_;
        float a0 = h[((size_t)(og * OB_ + o) * C_ + 2 * cp)     * KK_ + ij];
        float a1 = h[((size_t)(og * OB_ + o) * C_ + 2 * cp + 1) * KK_ + ij];
        hpack[(size_t)(og * NCP_ + cp) * HBLK_ + p * HPH_ + jj * OB_ + o] =
            packq(q16(a0), q16(a1));
    }
}

// ---------------- main kernel ------------------------------------------------
__global__ __launch_bounds__(NT_, 7)
void dilate_main(const unsigned* __restrict__ fpad,
                 const unsigned* __restrict__ hpack,
                 float* __restrict__ out) {
    const int tx  = threadIdx.x;           // 0..23
    const int ty  = threadIdx.y;           // 0..15
    const int ry  = ty & (RT_ - 1);        // 0..7
    const int g   = ty >> 3;               // 0..1, wave-uniform (192-thr groups)
    const int gu  = __builtin_amdgcn_readfirstlane(g);

    const int ytile = blockIdx.x;          // 0..11
    const int og    = blockIdx.y;          // 0..15
    const int b     = blockIdx.z;          // 0..7
    const int y0 = ytile * RT_;
    const int o0 = og * OB_;
    const int x0 = XR_ * tx;               // 0..92
    const int yb = y0 + ry;

    __shared__ unsigned short comb[OB_ * XR_][RT_ * TX_];   // 8 x 192 x 2 = 3072 B

    int acc[OB_][XR_];
#pragma unroll
    for (int o = 0; o < OB_; ++o)
#pragma unroll
        for (int xx = 0; xx < XR_; ++xx) acc[o][xx] = (int)NEGPACK_;

    const int cp0v = g * CPG_;    // vector copy for window addressing
    const int cp0s = gu * CPG_;   // scalar copy for h addressing
    const unsigned* hpb = hpack + (size_t)(og * NCP_ + cp0s) * HBLK_;
    const unsigned* pvb = fpad + (size_t)(b * NCP_ + cp0v) * PLSZ_ + yb * PW_ + x0;

    sv8 hA0; sv2 hA1;           // "even" phase h buffer (10 dw)
    sv8 hB0; sv2 hB1;           // "odd" phase h buffer
    uv4 winA[2], winB[2];       // 2 row buffers, 8 dwords each

    // prologue: h phase 0 of cp 0; window row 0 of cp 0 into winA.
    // vm outstanding entering loop = 2; each phase issues 2 then waits vmcnt(2).
    HLOADM(hA0, hA1, hpb, "0x0", "0x20");
    WLOADM(winA[0], winA[1], pvb, "0", "16");

#pragma unroll 1
    for (int cpi = 0; cpi < CPG_; cpi += 2) {
        const unsigned* hb0 = hpb + (size_t)cpi * HBLK_;
        const unsigned* hb1 = hb0 + HBLK_;
        const unsigned* hb2 = (cpi + 2 < CPG_) ? hb1 + HBLK_ : hb1;   // tail clamp
        const unsigned* pv0 = pvb + (size_t)cpi * PLSZ_;
        const unsigned* pv1 = pv0 + PLSZ_;
        const unsigned* pv2 = (cpi + 2 < CPG_) ? pv1 + PLSZ_ : pv1;   // tail clamp

        // k: body phase 0..9 (cp pair, 5 rows each); prefetch = phase k+1.
        // row offsets: r*PW_*4 = r*416 (+16 for second half).
        PHASE(hA0,hA1, hB0,hB1, hb0, "0x40","0x60",   winA, winB, pv0, "416","432");
        PHASE(hB0,hB1, hA0,hA1, hb0, "0x80","0xa0",   winB, winA, pv0, "832","848");
        PHASE(hA0,hA1, hB0,hB1, hb0, "0xc0","0xe0",   winA, winB, pv0, "1248","1264");
        PHASE(hB0,hB1, hA0,hA1, hb0, "0x100","0x120", winB, winA, pv0, "1664","1680");
        PHASE(hA0,hA1, hB0,hB1, hb1, "0x0","0x20",    winA, winB, pv1, "0","16");
        PHASE(hB0,hB1, hA0,hA1, hb1, "0x40","0x60",   winB, winA, pv1, "416","432");
        PHASE(hA0,hA1, hB0,hB1, hb1, "0x80","0xa0",   winA, winB, pv1, "832","848");
        PHASE(hB0,hB1, hA0,hA1, hb1, "0xc0","0xe0",   winB, winA, pv1, "1248","1264");
        PHASE(hA0,hA1, hB0,hB1, hb1, "0x100","0x120", winA, winB, pv1, "1664","1680");
        PHASE(hB0,hB1, hA0,hA1, hb2, "0x0","0x20",    winB, winA, pv2, "0","16");
    }

    // Drain the tail's in-flight junk prefetches (winA row + hA phase)
    // BEFORE regalloc may reuse those registers in the epilogue.
    asm volatile("s_waitcnt vmcnt(0) lgkmcnt(0)"
                 : "+v"(winA[0]), "+v"(winA[1]), "+s"(hA0), "+s"(hA1));

    // ---- reduce c-pair halves to scalar i16 ----------------------------------
    short red[OB_][XR_];
#pragma unroll
    for (int o = 0; o < OB_; ++o)
#pragma unroll
        for (int xx = 0; xx < XR_; ++xx) {
            short a = (short)(acc[o][xx] & 0xffff);
            short b2 = (short)(((unsigned)acc[o][xx]) >> 16);
            red[o][xx] = (a > b2) ? a : b2;
        }

    // ---- combine the two c-groups via LDS ------------------------------------
    const int t192 = ry * TX_ + tx;   // 0..191 within group
    if (g == 1) {
#pragma unroll
        for (int o = 0; o < OB_; ++o)
#pragma unroll
            for (int xx = 0; xx < XR_; ++xx)
                comb[o * XR_ + xx][t192] = (unsigned short)red[o][xx];
    }
    __syncthreads();
    if (g == 0) {
        const int y = yb;
#pragma unroll
        for (int o = 0; o < OB_; ++o) {
            float r[XR_];
#pragma unroll
            for (int xx = 0; xx < XR_; ++xx) {
                short m  = red[o][xx];
                short v0 = (short)comb[o * XR_ + xx][t192];
                m = (v0 > m) ? v0 : m;
                r[xx] = (float)m * INVSCALE_;
            }
            float4 v = make_float4(r[0], r[1], r[2], r[3]);
            *(float4*)&out[(((size_t)b * O_ + (o0 + o)) * H_ + y) * W_ + x0] = v;
        }
    }
}

// ---------------- fallback (no workspace): correctness-only ------------------
__global__ __launch_bounds__(256)
void dilate_naive(const float* __restrict__ f, const float* __restrict__ h,
                  float* __restrict__ out) {
    const int idx = blockIdx.x * 256 + threadIdx.x;
    if (idx >= B_ * O_ * H_ * W_) return;
    const int x = idx % W_;
    const int y = (idx / W_) % H_;
    const int o = (idx / (W_ * H_)) % O_;
    const int b = idx / (W_ * H_ * O_);
    float m = -3.0e38f;
    for (int c = 0; c < C_; ++c)
        for (int i = 0; i < K_; ++i)
            for (int j = 0; j < K_; ++j) {
                int yy = y + i - 2, xc = x + j - 2;
                if ((unsigned)yy < H_ && (unsigned)xc < W_) {
                    float v = f[((size_t)(b * C_ + c) * H_ + yy) * W_ + xc] +
                              h[((size_t)o * C_ + c) * KK_ + i * K_ + j];
                    m = fmaxf(m, v);
                }
            }
    out[idx] = m;
}

extern "C" void kernel_launch(void* const* d_in, const int* in_sizes, int n_in,
                              void* d_out, int out_size, void* d_ws, size_t ws_size,
                              hipStream_t stream) {
    const float* f = (const float*)d_in[0];
    const float* h = (const float*)d_in[1];
    float* out = (float*)d_out;

    const size_t need = FPAD_BYTES + (size_t)HPACK_DW * 4;
    if (ws_size >= need) {
        unsigned* fpad  = (unsigned*)d_ws;
        unsigned* hpack = (unsigned*)((char*)d_ws + FPAD_BYTES);
        dim3 pgrid((PLSZ_ + 255) / 256, NCP_, B_ + 1);   // z=B_ slice packs h
        hipLaunchKernelGGL(prep_kernel, pgrid, dim3(256), 0, stream,
                           f, h, fpad, hpack);
        dim3 mgrid(H_ / RT_, NOG_, B_);       // (12, 16, 8) = 1536 blocks
        dim3 mblock(TX_, TY_);                // 384 threads = 6 waves
        hipLaunchKernelGGL(dilate_main, mgrid, mblock, 0, stream,
                           fpad, hpack, out);
    } else {
        hipLaunchKernelGGL(dilate_naive,
                           dim3((B_ * O_ * H_ * W_ + 255) / 256), dim3(256),
                           0, stream, f, h, out);
    }
}